// Round 20
// baseline (954.934 us; speedup 1.0000x reference)
//
#include <hip/hip_runtime.h>

#define N0c 100000
#define N1c 20000
#define Ec 320000
#define NBLK ((Ec + 1023) / 1024)

typedef _Float16 f16;
typedef _Float16 f16x2 __attribute__((ext_vector_type(2)));

#define LOG2E 1.442695040888963f

__device__ __forceinline__ float tanh_(float x) {
    return 2.f * __builtin_amdgcn_rcpf(1.f + __builtin_amdgcn_exp2f(-2.f * LOG2E * x)) - 1.f;
}
__device__ __forceinline__ float dot2(uint w, uint v, float acc) {
#if __has_builtin(__builtin_amdgcn_fdot2)
    return __builtin_amdgcn_fdot2(__builtin_bit_cast(f16x2, w),
                                  __builtin_bit_cast(f16x2, v), acc, false);
#else
    f16x2 a = __builtin_bit_cast(f16x2, w);
    f16x2 b = __builtin_bit_cast(f16x2, v);
    return acc + (float)a[0] * (float)b[0] + (float)a[1] * (float)b[1];
#endif
}
__device__ __forceinline__ uint packh(float a, float b) {
    f16x2 p;
    p[0] = (f16)a;
    p[1] = (f16)b;
    return __builtin_bit_cast(uint, p);
}

// ---------------- length bucketing (deterministic counting sort) -----------
__global__ void count_kernel(const int* __restrict__ elen, int* __restrict__ bc) {
    __shared__ int h[8];
    if (threadIdx.x < 8) h[threadIdx.x] = 0;
    __syncthreads();
    const int base = blockIdx.x * 1024;
    for (int i = threadIdx.x; i < 1024; i += 256) {
        int e = base + i;
        if (e < Ec) atomicAdd(&h[elen[e] - 1], 1);
    }
    __syncthreads();
    if (threadIdx.x < 8) bc[blockIdx.x * 8 + threadIdx.x] = h[threadIdx.x];
}

__global__ void offs_kernel(const int* __restrict__ bc, int* __restrict__ bo) {
    __shared__ int s[NBLK * 8];
    __shared__ int base[8];
    const int tid = threadIdx.x;
    for (int i = tid; i < NBLK * 8; i += 256) s[i] = bc[i];
    __syncthreads();
    if (tid == 0) {
        int tot[8];
        for (int b = 0; b < 8; ++b) {
            int t = 0;
            for (int blk = 0; blk < NBLK; ++blk) t += s[blk * 8 + b];
            tot[b] = t;
        }
        int run = 0;
        for (int b = 0; b < 8; ++b) { base[b] = run; run += tot[b]; }
    }
    __syncthreads();
    if (tid < 8) {
        int run = base[tid];
        for (int blk = 0; blk < NBLK; ++blk) {
            int t = s[blk * 8 + tid];
            s[blk * 8 + tid] = run;
            run += t;
        }
    }
    __syncthreads();
    for (int i = tid; i < NBLK * 8; i += 256) bo[i] = s[i];
}

__global__ void scatter2_kernel(const int* __restrict__ elen, const int* __restrict__ bo,
                                int* __restrict__ lperm, int* __restrict__ lenq) {
    __shared__ int cnt[256][9];
    const int tid = threadIdx.x;
    const int base = blockIdx.x * 1024 + tid * 4;
    int lens[4];
    int lc0 = 0, lc1 = 0, lc2 = 0, lc3 = 0, lc4 = 0, lc5 = 0, lc6 = 0, lc7 = 0;
    #pragma unroll
    for (int j = 0; j < 4; ++j) {
        int e = base + j;
        int l = (e < Ec) ? elen[e] - 1 : -1;
        lens[j] = l;
        lc0 += (l == 0); lc1 += (l == 1); lc2 += (l == 2); lc3 += (l == 3);
        lc4 += (l == 4); lc5 += (l == 5); lc6 += (l == 6); lc7 += (l == 7);
    }
    cnt[tid][0] = lc0; cnt[tid][1] = lc1; cnt[tid][2] = lc2; cnt[tid][3] = lc3;
    cnt[tid][4] = lc4; cnt[tid][5] = lc5; cnt[tid][6] = lc6; cnt[tid][7] = lc7;
    __syncthreads();
    if (tid < 8) {
        int run = bo[blockIdx.x * 8 + tid];
        for (int i = 0; i < 256; ++i) {
            int t = cnt[i][tid];
            cnt[i][tid] = run;
            run += t;
        }
    }
    __syncthreads();
    #pragma unroll
    for (int b = 0; b < 8; ++b) {
        int p = cnt[tid][b];
        #pragma unroll
        for (int j = 0; j < 4; ++j) {
            if (lens[j] == b) { lperm[p] = base + j; lenq[p] = b + 1; ++p; }
        }
    }
}

// ---------------- dst bucketing (for node segment-sum) ---------------------
__global__ void dhist_kernel(const int* __restrict__ dst, int* __restrict__ hist) {
    int e = blockIdx.x * blockDim.x + threadIdx.x;
    if (e < Ec) atomicAdd(&hist[dst[e]], 1);
}

__global__ void dscan_kernel(int* __restrict__ hist) {
    __shared__ int s[N1c];
    __shared__ int psum[256];
    const int tid = threadIdx.x;
    const int CH = (N1c + 255) / 256;
    for (int i = tid; i < N1c; i += 256) s[i] = hist[i];
    __syncthreads();
    int loc = 0;
    #pragma unroll 1
    for (int j = 0; j < CH; ++j) {
        int i = tid * CH + j;
        if (i < N1c) loc += s[i];
    }
    psum[tid] = loc;
    __syncthreads();
    if (tid == 0) {
        int run = 0;
        for (int t = 0; t < 256; ++t) { int v = psum[t]; psum[t] = run; run += v; }
    }
    __syncthreads();
    int run = psum[tid];
    #pragma unroll 1
    for (int j = 0; j < CH; ++j) {
        int i = tid * CH + j;
        if (i < N1c) { int v = s[i]; s[i] = run; run += v; }
    }
    __syncthreads();
    for (int i = tid; i < N1c; i += 256) hist[i] = s[i];
}

__global__ void dscatter_kernel(const int* __restrict__ dst, int* __restrict__ cursor,
                                int* __restrict__ perm) {
    int e = blockIdx.x * blockDim.x + threadIdx.x;
    if (e < Ec) {
        int pos = atomicAdd(&cursor[dst[e]], 1);
        perm[pos] = e;
    }
}

// ---------------- weight prep: gate-pre-scaled packed f16 pairs ------------
__global__ void wprep_kernel(const float* __restrict__ Whh, const float* __restrict__ Wih,
                             const float* __restrict__ eW,
                             uint* __restrict__ wpk, uint* __restrict__ ewc) {
    int idx = blockIdx.x * 256 + threadIdx.x;
    if (idx < 40 * 256) {
        int r4 = idx >> 8, l = (idx >> 2) & 63, i = idx & 3;
        float s = (i == 2) ? (-2.f * LOG2E) : (-LOG2E);
        uint v;
        if (r4 < 32)
            v = packh(s * Whh[(2 * r4) * 256 + i * 64 + l],
                      s * Whh[(2 * r4 + 1) * 256 + i * 64 + l]);
        else {
            int kp = r4 - 32;
            v = packh(s * Wih[(2 * kp) * 256 + i * 64 + l],
                      s * Wih[(2 * kp + 1) * 256 + i * 64 + l]);
        }
        wpk[idx] = v;
    }
    if (idx < 24 * 256) {
        int c4 = idx >> 8, l = (idx >> 2) & 63, i = idx & 3;
        int cp = c4 * 4 + i;
        ewc[idx] = packh(eW[(2 * cp) * 64 + l], eW[(2 * cp + 1) * 64 + l]);
    }
}

// ---------------- X pre-pack in SORTED order: Xpk[pos][t][8] ---------------
__global__ void xprep_kernel(const float* __restrict__ ef, const float* __restrict__ st,
                             const int* __restrict__ lperm, uint* __restrict__ Xpk) {
    int idx = blockIdx.x * 256 + threadIdx.x;   // pos*8 + t
    int i = idx >> 3, t = idx & 7;
    int e = lperm[i];
    float v[16];
    #pragma unroll
    for (int f = 0; f < 15; ++f) v[f] = ef[(size_t)e * 120 + t * 15 + f];
    v[15] = st[(size_t)e * 8 + t];
    uint* dst = Xpk + (size_t)idx * 8;
    #pragma unroll
    for (int j = 0; j < 8; ++j) dst[j] = packh(v[2 * j], v[2 * j + 1]);
}

// ---------------- LSTM8: 8 length-sorted edges per wave, weights in LDS ----
// R19 was VALU-issue bound (86% busy, 4 edges). 8 edges/wave halves the
// per-edge weight-load issue cost and doubles independent dot2 chains per
// load (ILP). 512-thread blocks: 8 waves share one 40 KB LDS weight copy.

__global__ __launch_bounds__(512)
void lstm8_kernel(const uint4* __restrict__ wpk4, const float* __restrict__ lb,
                  const uint* __restrict__ Xpk, const int* __restrict__ lperm,
                  const int* __restrict__ lenq, f16* __restrict__ hb)
{
    __shared__ __align__(16) uint4 sW[2560];      // 40 KB: [chunk<40][lane]
    __shared__ __align__(16) f16 sH[8][8 * 64];   // [wave][edge][unit], 8 KB

    const int tid = threadIdx.x;
    #pragma unroll
    for (int i = 0; i < 5; ++i) sW[i * 512 + tid] = wpk4[i * 512 + tid];
    __syncthreads();

    const int lane = tid & 63;
    const int wv = tid >> 6;

    const float b0 = -LOG2E * lb[lane];
    const float b1 = -LOG2E * lb[64 + lane];
    const float b2 = -2.f * LOG2E * lb[128 + lane];
    const float b3 = -LOG2E * lb[192 + lane];
    f16* myH = sH[wv];
    const uint4* wl = sW + lane;   // chunk j at wl[j*64]

    const int nT = Ec / 8;   // 40000 tiles of 8 sorted edges
    for (int tile = blockIdx.x * 8 + wv; tile < nT; tile += gridDim.x * 8) {
        const int p0 = tile * 8;
        int oe[8], ln[8];
        #pragma unroll
        for (int j = 0; j < 8; ++j) { oe[j] = lperm[p0 + j]; ln[j] = lenq[p0 + j]; }
        int tmax = ln[0];
        #pragma unroll
        for (int j = 1; j < 8; ++j) tmax = max(tmax, ln[j]);

        const uint* xr = Xpk + (size_t)p0 * 64;   // 8 edges contiguous

        float h8[8], c8[8];
        #pragma unroll
        for (int j = 0; j < 8; ++j) { h8[j] = 0.f; c8[j] = 0.f; }

        for (int t = 0; t < tmax; ++t) {
            float a0[8], a1[8], a2[8], a3[8];
            #pragma unroll
            for (int j = 0; j < 8; ++j) { a0[j] = b0; a1[j] = b1; a2[j] = b2; a3[j] = b3; }

            // ---- h-part first (t>0): 8 h-chunks x 4 weight chunks ----
            if (t > 0) {
                #pragma unroll
                for (int jb = 0; jb < 8; ++jb) {
                    uint4 hq[8];
                    #pragma unroll
                    for (int j = 0; j < 8; ++j)
                        hq[j] = *(const uint4*)(myH + j * 64 + jb * 8);
                    #pragma unroll
                    for (int i = 0; i < 4; ++i) {
                        uint4 w = wl[(jb * 4 + i) * 64];
                        #pragma unroll
                        for (int j = 0; j < 8; ++j) {
                            uint hp = (i == 0) ? hq[j].x : (i == 1) ? hq[j].y
                                    : (i == 2) ? hq[j].z : hq[j].w;
                            a0[j] = dot2(w.x, hp, a0[j]);
                            a1[j] = dot2(w.y, hp, a1[j]);
                            a2[j] = dot2(w.z, hp, a2[j]);
                            a3[j] = dot2(w.w, hp, a3[j]);
                        }
                    }
                }
            }

            // ---- x-part: chunk-outer, shared w, JIT uniform x loads ----
            #pragma unroll
            for (int k4 = 0; k4 < 8; ++k4) {
                uint4 w = wl[(32 + k4) * 64];
                #pragma unroll
                for (int j = 0; j < 8; ++j) {
                    uint xv = xr[j * 64 + t * 8 + k4];
                    a0[j] = dot2(w.x, xv, a0[j]);
                    a1[j] = dot2(w.y, xv, a1[j]);
                    a2[j] = dot2(w.z, xv, a2[j]);
                    a3[j] = dot2(w.w, xv, a3[j]);
                }
            }

            // ---- gates (pre-scaled) + state update (per-edge len mask) ----
            #pragma unroll
            for (int j = 0; j < 8; ++j) {
                float ig = __builtin_amdgcn_rcpf(1.f + __builtin_amdgcn_exp2f(a0[j]));
                float fg = __builtin_amdgcn_rcpf(1.f + __builtin_amdgcn_exp2f(a1[j]));
                float gg = 2.f * __builtin_amdgcn_rcpf(1.f + __builtin_amdgcn_exp2f(a2[j])) - 1.f;
                float og = __builtin_amdgcn_rcpf(1.f + __builtin_amdgcn_exp2f(a3[j]));
                float cn = fg * c8[j] + ig * gg;
                float hn = og * tanh_(cn);
                if (t < ln[j]) { c8[j] = cn; h8[j] = hn; }
            }
            if (t + 1 < tmax) {
                #pragma unroll
                for (int j = 0; j < 8; ++j) myH[j * 64 + lane] = (f16)h8[j];
            }
        }

        #pragma unroll
        for (int j = 0; j < 8; ++j)
            hb[(size_t)oe[j] * 64 + lane] = (f16)h8[j];
    }
}

// ---------------- MLP: wave-per-edge, eW in registers, f16 dot2 ------------
__global__ __launch_bounds__(256, 2)
void mlp_kernel(const float* __restrict__ nf, const float* __restrict__ pw,
                const uint4* __restrict__ ewc4, const float* __restrict__ ebias,
                const int* __restrict__ src, const f16* __restrict__ hb,
                f16* __restrict__ mbuf)
{
    __shared__ __align__(16) f16 sCat[4][192];
    const int lane = threadIdx.x & 63;
    const int wv = threadIdx.x >> 6;

    uint ew[24][4];
    #pragma unroll
    for (int i = 0; i < 24; ++i) {
        uint4 v = ewc4[i * 64 + lane];
        ew[i][0] = v.x; ew[i][1] = v.y; ew[i][2] = v.z; ew[i][3] = v.w;
    }
    const float pwl = pw[lane], pwh = pw[64 + lane];
    const float ebl = ebias[lane];

    f16* myCat = sCat[wv];
    const int wid = blockIdx.x * 4 + wv;
    const int stride = gridDim.x * 4;
    for (int e = wid; e < Ec; e += stride) {
        const int s = src[e];
        float hs0 = nf[(size_t)s * 128 + lane];
        float hs1 = nf[(size_t)s * 128 + 64 + lane];
        float part = hs0 * pwl + hs1 * pwh;
        #pragma unroll
        for (int off = 32; off; off >>= 1) part += __shfl_xor(part, off);
        float he = (float)hb[(size_t)e * 64 + lane];
        myCat[lane] = (f16)(hs0 - part * pwl);
        myCat[64 + lane] = (f16)(hs1 - part * pwh);
        myCat[128 + lane] = (f16)he;
        const uint4* cp = (const uint4*)myCat;
        float m0 = 0.f, m1 = 0.f, m2 = 0.f, m3 = 0.f;
        #pragma unroll
        for (int i = 0; i < 24; ++i) {
            uint4 q = cp[i];
            m0 = dot2(ew[i][0], q.x, m0);
            m1 = dot2(ew[i][1], q.y, m1);
            m2 = dot2(ew[i][2], q.z, m2);
            m3 = dot2(ew[i][3], q.w, m3);
        }
        float m = fmaxf(m0 + m1 + m2 + m3 + ebl, 0.f);
        mbuf[(size_t)e * 64 + lane] = (f16)m;
    }
}

// ---------------- Node kernel: segment-sum of m + node math ----------------
#define NB_WAVES 8
#define NB_THREADS (NB_WAVES * 64)
__global__ __launch_bounds__(NB_THREADS, 1)
void node_kernel(const float* __restrict__ nf,
                 const float* __restrict__ sgn,
                 const float* __restrict__ eW,
                 const float* __restrict__ ebias,
                 const float* __restrict__ nW,
                 const float* __restrict__ nbias,
                 const float* __restrict__ fcW,
                 const float* __restrict__ fcb,
                 const int* __restrict__ lnid,
                 const int* __restrict__ hist,
                 const int* __restrict__ perm,
                 const f16* __restrict__ m,
                 float* __restrict__ out,
                 int nWavesTotal)
{
    __shared__ float sEW[128 * 64];
    __shared__ float sNW[192 * 64];
    __shared__ float sFC[64 * 16];
    __shared__ float sCat[NB_WAVES][192];
    __shared__ float sAct[NB_WAVES][64];

    const int tid = threadIdx.x;
    for (int idx = tid; idx < 128 * 64; idx += NB_THREADS) sEW[idx] = eW[idx];
    for (int idx = tid; idx < 192 * 64; idx += NB_THREADS) sNW[idx] = nW[idx];
    for (int idx = tid; idx < 64 * 16; idx += NB_THREADS) sFC[idx] = fcW[idx];
    __syncthreads();

    const int lane = tid & 63;
    const int wv = tid >> 6;
    const int gwave = blockIdx.x * NB_WAVES + wv;

    const float ebv = ebias[lane];
    const float nbv = nbias[lane];
    const float fcbv = (lane < 16) ? fcb[lane] : 0.f;

    for (int n = gwave; n < N1c; n += nWavesTotal) {
        const int nid = lnid[n];
        float sh0 = nf[(size_t)nid * 128 + lane];
        float sh1 = nf[(size_t)nid * 128 + 64 + lane];
        sCat[wv][lane] = sh0;
        sCat[wv][64 + lane] = sh1;

        float tmp = ebv;
        #pragma unroll 8
        for (int cc = 0; cc < 128; ++cc) tmp += sCat[wv][cc] * sEW[cc * 64 + lane];

        const int o0 = (n == 0) ? 0 : hist[n - 1];
        const int o1 = hist[n];
        float av = 0.f;
        for (int base = o0; base < o1; base += 64) {
            int cnt = min(64, o1 - base);
            int pk = (lane < cnt) ? perm[base + lane] : 0;
            for (int j = 0; j < cnt; ++j) {
                int pe = __shfl(pk, j);
                av += (float)m[(size_t)pe * 64 + lane];
            }
        }

        float hu = (av - tmp) * sgn[n];
        sCat[wv][128 + lane] = hu;

        float acc = nbv;
        #pragma unroll 8
        for (int cc = 0; cc < 192; ++cc) acc += sCat[wv][cc] * sNW[cc * 64 + lane];
        acc = fmaxf(acc, 0.f);
        sAct[wv][lane] = acc;

        if (lane < 16) {
            float o = fcbv;
            #pragma unroll
            for (int j = 0; j < 64; ++j) o += sAct[wv][j] * sFC[j * 16 + lane];
            out[(size_t)n * 16 + lane] = o;
        }
    }
}

extern "C" void kernel_launch(void* const* d_in, const int* in_sizes, int n_in,
                              void* d_out, int out_size, void* d_ws, size_t ws_size,
                              hipStream_t stream) {
    const float* nf  = (const float*)d_in[0];
    const float* ef  = (const float*)d_in[1];
    const float* st  = (const float*)d_in[2];
    const float* sgn = (const float*)d_in[3];
    const float* pw  = (const float*)d_in[4];
    const float* Wih = (const float*)d_in[5];
    const float* Whh = (const float*)d_in[6];
    const float* lb  = (const float*)d_in[7];
    const float* eW  = (const float*)d_in[8];
    const float* eb  = (const float*)d_in[9];
    const float* nW  = (const float*)d_in[10];
    const float* nb  = (const float*)d_in[11];
    const float* fcW = (const float*)d_in[12];
    const float* fcb = (const float*)d_in[13];
    const int* elen = (const int*)d_in[14];
    const int* src  = (const int*)d_in[15];
    const int* dst  = (const int*)d_in[16];
    const int* lnid = (const int*)d_in[17];

    float* out = (float*)d_out;

    // ws layout (bytes)
    char* base = (char*)d_ws;
    int*  hist  = (int*) (base + 0);           // 80 KB
    int*  dperm = (int*) (base + 81920);       // -> 1392640
    int*  bc    = (int*) (base + 1392640);     // 16 KB
    int*  bo    = (int*) (base + 1409024);     // 16 KB
    int*  lperm = (int*) (base + 1425408);     // -> 2736128
    int*  lenq  = (int*) (base + 2736128);     // -> 4046848
    uint* wpk   = (uint*)(base + 4046848);     // 40 KB -> 4112384 (padded)
    uint* ewc   = (uint*)(base + 4112384);     // 24.5 KB -> 4145152
    uint* Xpk   = (uint*)(base + 4145152);     // 81.92 MB -> 86065152
    f16*  hb    = (f16*) (base + 86065152);    // 40.96 MB -> 127025152
    f16*  mbuf  = (f16*) (base + 127025152);   // 40.96 MB -> 167985152

    hipMemsetAsync(hist, 0, 81920, stream);

    // length sort (for lstm8 tiles + sorted Xpk)
    count_kernel<<<NBLK, 256, 0, stream>>>(elen, bc);
    offs_kernel<<<1, 256, 0, stream>>>(bc, bo);
    scatter2_kernel<<<NBLK, 256, 0, stream>>>(elen, bo, lperm, lenq);

    // dst sort (for node segment-sum)
    dhist_kernel<<<1250, 256, 0, stream>>>(dst, hist);
    dscan_kernel<<<1, 256, 0, stream>>>(hist);
    dscatter_kernel<<<1250, 256, 0, stream>>>(dst, hist, dperm);

    wprep_kernel<<<40, 256, 0, stream>>>(Whh, Wih, eW, wpk, ewc);
    xprep_kernel<<<10000, 256, 0, stream>>>(ef, st, lperm, Xpk);

    lstm8_kernel<<<1250, 512, 0, stream>>>((const uint4*)wpk, lb, Xpk, lperm, lenq, hb);

    mlp_kernel<<<1024, 256, 0, stream>>>(nf, pw, (const uint4*)ewc, eb, src, hb, mbuf);

    node_kernel<<<512, NB_THREADS, 0, stream>>>(
        nf, sgn, eW, eb, nW, nb, fcW, fcb, lnid, hist, dperm, mbuf, out,
        512 * NB_WAVES);
}

// Round 21
// 866.769 us; speedup vs baseline: 1.1017x; 1.1017x over previous
//
#include <hip/hip_runtime.h>

#define N0c 100000
#define N1c 20000
#define Ec 320000
#define NBLK ((Ec + 1023) / 1024)

typedef _Float16 f16;
typedef _Float16 f16x2 __attribute__((ext_vector_type(2)));

#define LOG2E 1.442695040888963f

__device__ __forceinline__ float tanh_(float x) {
    return 2.f * __builtin_amdgcn_rcpf(1.f + __builtin_amdgcn_exp2f(-2.f * LOG2E * x)) - 1.f;
}
__device__ __forceinline__ float dot2(uint w, uint v, float acc) {
#if __has_builtin(__builtin_amdgcn_fdot2)
    return __builtin_amdgcn_fdot2(__builtin_bit_cast(f16x2, w),
                                  __builtin_bit_cast(f16x2, v), acc, false);
#else
    f16x2 a = __builtin_bit_cast(f16x2, w);
    f16x2 b = __builtin_bit_cast(f16x2, v);
    return acc + (float)a[0] * (float)b[0] + (float)a[1] * (float)b[1];
#endif
}
__device__ __forceinline__ uint packh(float a, float b) {
    f16x2 p;
    p[0] = (f16)a;
    p[1] = (f16)b;
    return __builtin_bit_cast(uint, p);
}

// ---------------- length bucketing (deterministic counting sort) -----------
__global__ void count_kernel(const int* __restrict__ elen, int* __restrict__ bc) {
    __shared__ int h[8];
    if (threadIdx.x < 8) h[threadIdx.x] = 0;
    __syncthreads();
    const int base = blockIdx.x * 1024;
    for (int i = threadIdx.x; i < 1024; i += 256) {
        int e = base + i;
        if (e < Ec) atomicAdd(&h[elen[e] - 1], 1);
    }
    __syncthreads();
    if (threadIdx.x < 8) bc[blockIdx.x * 8 + threadIdx.x] = h[threadIdx.x];
}

__global__ void offs_kernel(const int* __restrict__ bc, int* __restrict__ bo) {
    __shared__ int s[NBLK * 8];
    __shared__ int base[8];
    const int tid = threadIdx.x;
    for (int i = tid; i < NBLK * 8; i += 256) s[i] = bc[i];
    __syncthreads();
    if (tid == 0) {
        int tot[8];
        for (int b = 0; b < 8; ++b) {
            int t = 0;
            for (int blk = 0; blk < NBLK; ++blk) t += s[blk * 8 + b];
            tot[b] = t;
        }
        int run = 0;
        for (int b = 0; b < 8; ++b) { base[b] = run; run += tot[b]; }
    }
    __syncthreads();
    if (tid < 8) {
        int run = base[tid];
        for (int blk = 0; blk < NBLK; ++blk) {
            int t = s[blk * 8 + tid];
            s[blk * 8 + tid] = run;
            run += t;
        }
    }
    __syncthreads();
    for (int i = tid; i < NBLK * 8; i += 256) bo[i] = s[i];
}

__global__ void scatter2_kernel(const int* __restrict__ elen, const int* __restrict__ bo,
                                int* __restrict__ lperm, int* __restrict__ lenq) {
    __shared__ int cnt[256][9];
    const int tid = threadIdx.x;
    const int base = blockIdx.x * 1024 + tid * 4;
    int lens[4];
    int lc0 = 0, lc1 = 0, lc2 = 0, lc3 = 0, lc4 = 0, lc5 = 0, lc6 = 0, lc7 = 0;
    #pragma unroll
    for (int j = 0; j < 4; ++j) {
        int e = base + j;
        int l = (e < Ec) ? elen[e] - 1 : -1;
        lens[j] = l;
        lc0 += (l == 0); lc1 += (l == 1); lc2 += (l == 2); lc3 += (l == 3);
        lc4 += (l == 4); lc5 += (l == 5); lc6 += (l == 6); lc7 += (l == 7);
    }
    cnt[tid][0] = lc0; cnt[tid][1] = lc1; cnt[tid][2] = lc2; cnt[tid][3] = lc3;
    cnt[tid][4] = lc4; cnt[tid][5] = lc5; cnt[tid][6] = lc6; cnt[tid][7] = lc7;
    __syncthreads();
    if (tid < 8) {
        int run = bo[blockIdx.x * 8 + tid];
        for (int i = 0; i < 256; ++i) {
            int t = cnt[i][tid];
            cnt[i][tid] = run;
            run += t;
        }
    }
    __syncthreads();
    #pragma unroll
    for (int b = 0; b < 8; ++b) {
        int p = cnt[tid][b];
        #pragma unroll
        for (int j = 0; j < 4; ++j) {
            if (lens[j] == b) { lperm[p] = base + j; lenq[p] = b + 1; ++p; }
        }
    }
}

// ---------------- dst bucketing (for node segment-sum) ---------------------
__global__ void dhist_kernel(const int* __restrict__ dst, int* __restrict__ hist) {
    int e = blockIdx.x * blockDim.x + threadIdx.x;
    if (e < Ec) atomicAdd(&hist[dst[e]], 1);
}

__global__ void dscan_kernel(int* __restrict__ hist) {
    __shared__ int s[N1c];
    __shared__ int psum[256];
    const int tid = threadIdx.x;
    const int CH = (N1c + 255) / 256;
    for (int i = tid; i < N1c; i += 256) s[i] = hist[i];
    __syncthreads();
    int loc = 0;
    #pragma unroll 1
    for (int j = 0; j < CH; ++j) {
        int i = tid * CH + j;
        if (i < N1c) loc += s[i];
    }
    psum[tid] = loc;
    __syncthreads();
    if (tid == 0) {
        int run = 0;
        for (int t = 0; t < 256; ++t) { int v = psum[t]; psum[t] = run; run += v; }
    }
    __syncthreads();
    int run = psum[tid];
    #pragma unroll 1
    for (int j = 0; j < CH; ++j) {
        int i = tid * CH + j;
        if (i < N1c) { int v = s[i]; s[i] = run; run += v; }
    }
    __syncthreads();
    for (int i = tid; i < N1c; i += 256) hist[i] = s[i];
}

__global__ void dscatter_kernel(const int* __restrict__ dst, int* __restrict__ cursor,
                                int* __restrict__ perm) {
    int e = blockIdx.x * blockDim.x + threadIdx.x;
    if (e < Ec) {
        int pos = atomicAdd(&cursor[dst[e]], 1);
        perm[pos] = e;
    }
}

// ---------------- weight prep: gate-pre-scaled packed f16 pairs ------------
__global__ void wprep_kernel(const float* __restrict__ Whh, const float* __restrict__ Wih,
                             const float* __restrict__ eW,
                             uint* __restrict__ wpk, uint* __restrict__ ewc) {
    int idx = blockIdx.x * 256 + threadIdx.x;
    if (idx < 40 * 256) {
        int r4 = idx >> 8, l = (idx >> 2) & 63, i = idx & 3;
        float s = (i == 2) ? (-2.f * LOG2E) : (-LOG2E);
        uint v;
        if (r4 < 32)
            v = packh(s * Whh[(2 * r4) * 256 + i * 64 + l],
                      s * Whh[(2 * r4 + 1) * 256 + i * 64 + l]);
        else {
            int kp = r4 - 32;
            v = packh(s * Wih[(2 * kp) * 256 + i * 64 + l],
                      s * Wih[(2 * kp + 1) * 256 + i * 64 + l]);
        }
        wpk[idx] = v;
    }
    if (idx < 24 * 256) {
        int c4 = idx >> 8, l = (idx >> 2) & 63, i = idx & 3;
        int cp = c4 * 4 + i;
        ewc[idx] = packh(eW[(2 * cp) * 64 + l], eW[(2 * cp + 1) * 64 + l]);
    }
}

// ---------------- X pre-pack in SORTED order: Xpk[pos][t][8] ---------------
__global__ void xprep_kernel(const float* __restrict__ ef, const float* __restrict__ st,
                             const int* __restrict__ lperm, uint* __restrict__ Xpk) {
    int idx = blockIdx.x * 256 + threadIdx.x;   // pos*8 + t
    int i = idx >> 3, t = idx & 7;
    int e = lperm[i];
    float v[16];
    #pragma unroll
    for (int f = 0; f < 15; ++f) v[f] = ef[(size_t)e * 120 + t * 15 + f];
    v[15] = st[(size_t)e * 8 + t];
    uint* dst = Xpk + (size_t)idx * 8;
    #pragma unroll
    for (int j = 0; j < 8; ++j) dst[j] = packh(v[2 * j], v[2 * j + 1]);
}

// ---------------- LSTM4: 4 length-sorted edges per wave, weights in LDS ----
// (R19 verified best: 548 us, VGPR 68, VALUBusy 86%, FETCH/WRITE source-exact,
// zero bank conflicts. R20's 8-edge variant regressed -> reverted.)

__global__ __launch_bounds__(256)
void lstm4_kernel(const uint4* __restrict__ wpk4, const float* __restrict__ lb,
                  const uint* __restrict__ Xpk, const int* __restrict__ lperm,
                  const int* __restrict__ lenq, f16* __restrict__ hb)
{
    __shared__ __align__(16) uint4 sW[2560];      // 40 KB: [chunk<40][lane]
    __shared__ __align__(16) f16 sH[4][4 * 64];   // [wave][edge][unit], 2 KB

    const int tid = threadIdx.x;
    #pragma unroll
    for (int i = 0; i < 10; ++i) sW[i * 256 + tid] = wpk4[i * 256 + tid];
    __syncthreads();

    const int lane = tid & 63;
    const int wv = tid >> 6;

    const float b0 = -LOG2E * lb[lane];
    const float b1 = -LOG2E * lb[64 + lane];
    const float b2 = -2.f * LOG2E * lb[128 + lane];
    const float b3 = -LOG2E * lb[192 + lane];
    f16* myH = sH[wv];
    const uint4* wl = sW + lane;   // chunk j at wl[j*64]

    const int nT = Ec / 4;
    for (int tile = blockIdx.x * 4 + wv; tile < nT; tile += gridDim.x * 4) {
        const int p0 = tile * 4;
        const int oe0 = lperm[p0], oe1 = lperm[p0 + 1], oe2 = lperm[p0 + 2], oe3 = lperm[p0 + 3];
        const int l0 = lenq[p0], l1 = lenq[p0 + 1], l2 = lenq[p0 + 2], l3 = lenq[p0 + 3];
        const int tmax = max(max(l0, l1), max(l2, l3));

        const uint* xr = Xpk + (size_t)p0 * 64;

        float hA = 0.f, cA = 0.f, hB = 0.f, cB = 0.f;
        float hC = 0.f, cC = 0.f, hD = 0.f, cD = 0.f;

        for (int t = 0; t < tmax; ++t) {
            float a0A = b0, a1A = b1, a2A = b2, a3A = b3;
            float a0B = b0, a1B = b1, a2B = b2, a3B = b3;
            float a0C = b0, a1C = b1, a2C = b2, a3C = b3;
            float a0D = b0, a1D = b1, a2D = b2, a3D = b3;

            // ---- h-part first (t>0): 8 h-chunks x 4 weight chunks ----
            if (t > 0) {
                #pragma unroll
                for (int jb = 0; jb < 8; ++jb) {
                    uint4 hA4 = *(const uint4*)(myH + 0 * 64 + jb * 8);
                    uint4 hB4 = *(const uint4*)(myH + 1 * 64 + jb * 8);
                    uint4 hC4 = *(const uint4*)(myH + 2 * 64 + jb * 8);
                    uint4 hD4 = *(const uint4*)(myH + 3 * 64 + jb * 8);
                    #pragma unroll
                    for (int i = 0; i < 4; ++i) {
                        uint4 w = wl[(jb * 4 + i) * 64];
                        uint hpA = (i == 0) ? hA4.x : (i == 1) ? hA4.y : (i == 2) ? hA4.z : hA4.w;
                        uint hpB = (i == 0) ? hB4.x : (i == 1) ? hB4.y : (i == 2) ? hB4.z : hB4.w;
                        uint hpC = (i == 0) ? hC4.x : (i == 1) ? hC4.y : (i == 2) ? hC4.z : hC4.w;
                        uint hpD = (i == 0) ? hD4.x : (i == 1) ? hD4.y : (i == 2) ? hD4.z : hD4.w;
                        a0A = dot2(w.x, hpA, a0A); a1A = dot2(w.y, hpA, a1A);
                        a2A = dot2(w.z, hpA, a2A); a3A = dot2(w.w, hpA, a3A);
                        a0B = dot2(w.x, hpB, a0B); a1B = dot2(w.y, hpB, a1B);
                        a2B = dot2(w.z, hpB, a2B); a3B = dot2(w.w, hpB, a3B);
                        a0C = dot2(w.x, hpC, a0C); a1C = dot2(w.y, hpC, a1C);
                        a2C = dot2(w.z, hpC, a2C); a3C = dot2(w.w, hpC, a3C);
                        a0D = dot2(w.x, hpD, a0D); a1D = dot2(w.y, hpD, a1D);
                        a2D = dot2(w.z, hpD, a2D); a3D = dot2(w.w, hpD, a3D);
                    }
                }
            }

            // ---- x-part: chunk-outer, shared w, JIT uniform x loads ----
            #pragma unroll
            for (int k4 = 0; k4 < 8; ++k4) {
                uint4 w = wl[(32 + k4) * 64];
                uint xA = xr[t * 8 + k4];
                uint xB = xr[64 + t * 8 + k4];
                uint xC = xr[128 + t * 8 + k4];
                uint xD = xr[192 + t * 8 + k4];
                a0A = dot2(w.x, xA, a0A); a1A = dot2(w.y, xA, a1A);
                a2A = dot2(w.z, xA, a2A); a3A = dot2(w.w, xA, a3A);
                a0B = dot2(w.x, xB, a0B); a1B = dot2(w.y, xB, a1B);
                a2B = dot2(w.z, xB, a2B); a3B = dot2(w.w, xB, a3B);
                a0C = dot2(w.x, xC, a0C); a1C = dot2(w.y, xC, a1C);
                a2C = dot2(w.z, xC, a2C); a3C = dot2(w.w, xC, a3C);
                a0D = dot2(w.x, xD, a0D); a1D = dot2(w.y, xD, a1D);
                a2D = dot2(w.z, xD, a2D); a3D = dot2(w.w, xD, a3D);
            }

            // ---- gates (pre-scaled) + state update (per-edge len mask) ----
            {
                float ig = __builtin_amdgcn_rcpf(1.f + __builtin_amdgcn_exp2f(a0A));
                float fg = __builtin_amdgcn_rcpf(1.f + __builtin_amdgcn_exp2f(a1A));
                float gg = 2.f * __builtin_amdgcn_rcpf(1.f + __builtin_amdgcn_exp2f(a2A)) - 1.f;
                float og = __builtin_amdgcn_rcpf(1.f + __builtin_amdgcn_exp2f(a3A));
                float cn = fg * cA + ig * gg, hn = og * tanh_(cn);
                if (t < l0) { cA = cn; hA = hn; }
                ig = __builtin_amdgcn_rcpf(1.f + __builtin_amdgcn_exp2f(a0B));
                fg = __builtin_amdgcn_rcpf(1.f + __builtin_amdgcn_exp2f(a1B));
                gg = 2.f * __builtin_amdgcn_rcpf(1.f + __builtin_amdgcn_exp2f(a2B)) - 1.f;
                og = __builtin_amdgcn_rcpf(1.f + __builtin_amdgcn_exp2f(a3B));
                cn = fg * cB + ig * gg; hn = og * tanh_(cn);
                if (t < l1) { cB = cn; hB = hn; }
                ig = __builtin_amdgcn_rcpf(1.f + __builtin_amdgcn_exp2f(a0C));
                fg = __builtin_amdgcn_rcpf(1.f + __builtin_amdgcn_exp2f(a1C));
                gg = 2.f * __builtin_amdgcn_rcpf(1.f + __builtin_amdgcn_exp2f(a2C)) - 1.f;
                og = __builtin_amdgcn_rcpf(1.f + __builtin_amdgcn_exp2f(a3C));
                cn = fg * cC + ig * gg; hn = og * tanh_(cn);
                if (t < l2) { cC = cn; hC = hn; }
                ig = __builtin_amdgcn_rcpf(1.f + __builtin_amdgcn_exp2f(a0D));
                fg = __builtin_amdgcn_rcpf(1.f + __builtin_amdgcn_exp2f(a1D));
                gg = 2.f * __builtin_amdgcn_rcpf(1.f + __builtin_amdgcn_exp2f(a2D)) - 1.f;
                og = __builtin_amdgcn_rcpf(1.f + __builtin_amdgcn_exp2f(a3D));
                cn = fg * cD + ig * gg; hn = og * tanh_(cn);
                if (t < l3) { cD = cn; hD = hn; }
            }
            if (t + 1 < tmax) {
                myH[0 * 64 + lane] = (f16)hA;
                myH[1 * 64 + lane] = (f16)hB;
                myH[2 * 64 + lane] = (f16)hC;
                myH[3 * 64 + lane] = (f16)hD;
            }
        }

        hb[(size_t)oe0 * 64 + lane] = (f16)hA;
        hb[(size_t)oe1 * 64 + lane] = (f16)hB;
        hb[(size_t)oe2 * 64 + lane] = (f16)hC;
        hb[(size_t)oe3 * 64 + lane] = (f16)hD;
    }
}

// ---------------- MLP: wave-per-edge, eW in registers, f16 dot2 ------------
__global__ __launch_bounds__(256, 2)
void mlp_kernel(const float* __restrict__ nf, const float* __restrict__ pw,
                const uint4* __restrict__ ewc4, const float* __restrict__ ebias,
                const int* __restrict__ src, const f16* __restrict__ hb,
                f16* __restrict__ mbuf)
{
    __shared__ __align__(16) f16 sCat[4][192];
    const int lane = threadIdx.x & 63;
    const int wv = threadIdx.x >> 6;

    uint ew[24][4];
    #pragma unroll
    for (int i = 0; i < 24; ++i) {
        uint4 v = ewc4[i * 64 + lane];
        ew[i][0] = v.x; ew[i][1] = v.y; ew[i][2] = v.z; ew[i][3] = v.w;
    }
    const float pwl = pw[lane], pwh = pw[64 + lane];
    const float ebl = ebias[lane];

    f16* myCat = sCat[wv];
    const int wid = blockIdx.x * 4 + wv;
    const int stride = gridDim.x * 4;
    for (int e = wid; e < Ec; e += stride) {
        const int s = src[e];
        float hs0 = nf[(size_t)s * 128 + lane];
        float hs1 = nf[(size_t)s * 128 + 64 + lane];
        float part = hs0 * pwl + hs1 * pwh;
        #pragma unroll
        for (int off = 32; off; off >>= 1) part += __shfl_xor(part, off);
        float he = (float)hb[(size_t)e * 64 + lane];
        myCat[lane] = (f16)(hs0 - part * pwl);
        myCat[64 + lane] = (f16)(hs1 - part * pwh);
        myCat[128 + lane] = (f16)he;
        const uint4* cp = (const uint4*)myCat;
        float m0 = 0.f, m1 = 0.f, m2 = 0.f, m3 = 0.f;
        #pragma unroll
        for (int i = 0; i < 24; ++i) {
            uint4 q = cp[i];
            m0 = dot2(ew[i][0], q.x, m0);
            m1 = dot2(ew[i][1], q.y, m1);
            m2 = dot2(ew[i][2], q.z, m2);
            m3 = dot2(ew[i][3], q.w, m3);
        }
        float m = fmaxf(m0 + m1 + m2 + m3 + ebl, 0.f);
        mbuf[(size_t)e * 64 + lane] = (f16)m;
    }
}

// ---------------- Node kernel: segment-sum of m + node math ----------------
#define NB_WAVES 8
#define NB_THREADS (NB_WAVES * 64)
__global__ __launch_bounds__(NB_THREADS, 1)
void node_kernel(const float* __restrict__ nf,
                 const float* __restrict__ sgn,
                 const float* __restrict__ eW,
                 const float* __restrict__ ebias,
                 const float* __restrict__ nW,
                 const float* __restrict__ nbias,
                 const float* __restrict__ fcW,
                 const float* __restrict__ fcb,
                 const int* __restrict__ lnid,
                 const int* __restrict__ hist,
                 const int* __restrict__ perm,
                 const f16* __restrict__ m,
                 float* __restrict__ out,
                 int nWavesTotal)
{
    __shared__ float sEW[128 * 64];
    __shared__ float sNW[192 * 64];
    __shared__ float sFC[64 * 16];
    __shared__ float sCat[NB_WAVES][192];
    __shared__ float sAct[NB_WAVES][64];

    const int tid = threadIdx.x;
    for (int idx = tid; idx < 128 * 64; idx += NB_THREADS) sEW[idx] = eW[idx];
    for (int idx = tid; idx < 192 * 64; idx += NB_THREADS) sNW[idx] = nW[idx];
    for (int idx = tid; idx < 64 * 16; idx += NB_THREADS) sFC[idx] = fcW[idx];
    __syncthreads();

    const int lane = tid & 63;
    const int wv = tid >> 6;
    const int gwave = blockIdx.x * NB_WAVES + wv;

    const float ebv = ebias[lane];
    const float nbv = nbias[lane];
    const float fcbv = (lane < 16) ? fcb[lane] : 0.f;

    for (int n = gwave; n < N1c; n += nWavesTotal) {
        const int nid = lnid[n];
        float sh0 = nf[(size_t)nid * 128 + lane];
        float sh1 = nf[(size_t)nid * 128 + 64 + lane];
        sCat[wv][lane] = sh0;
        sCat[wv][64 + lane] = sh1;

        float tmp = ebv;
        #pragma unroll 8
        for (int cc = 0; cc < 128; ++cc) tmp += sCat[wv][cc] * sEW[cc * 64 + lane];

        const int o0 = (n == 0) ? 0 : hist[n - 1];
        const int o1 = hist[n];
        float av = 0.f;
        for (int base = o0; base < o1; base += 64) {
            int cnt = min(64, o1 - base);
            int pk = (lane < cnt) ? perm[base + lane] : 0;
            for (int j = 0; j < cnt; ++j) {
                int pe = __shfl(pk, j);
                av += (float)m[(size_t)pe * 64 + lane];
            }
        }

        float hu = (av - tmp) * sgn[n];
        sCat[wv][128 + lane] = hu;

        float acc = nbv;
        #pragma unroll 8
        for (int cc = 0; cc < 192; ++cc) acc += sCat[wv][cc] * sNW[cc * 64 + lane];
        acc = fmaxf(acc, 0.f);
        sAct[wv][lane] = acc;

        if (lane < 16) {
            float o = fcbv;
            #pragma unroll
            for (int j = 0; j < 64; ++j) o += sAct[wv][j] * sFC[j * 16 + lane];
            out[(size_t)n * 16 + lane] = o;
        }
    }
}

extern "C" void kernel_launch(void* const* d_in, const int* in_sizes, int n_in,
                              void* d_out, int out_size, void* d_ws, size_t ws_size,
                              hipStream_t stream) {
    const float* nf  = (const float*)d_in[0];
    const float* ef  = (const float*)d_in[1];
    const float* st  = (const float*)d_in[2];
    const float* sgn = (const float*)d_in[3];
    const float* pw  = (const float*)d_in[4];
    const float* Wih = (const float*)d_in[5];
    const float* Whh = (const float*)d_in[6];
    const float* lb  = (const float*)d_in[7];
    const float* eW  = (const float*)d_in[8];
    const float* eb  = (const float*)d_in[9];
    const float* nW  = (const float*)d_in[10];
    const float* nb  = (const float*)d_in[11];
    const float* fcW = (const float*)d_in[12];
    const float* fcb = (const float*)d_in[13];
    const int* elen = (const int*)d_in[14];
    const int* src  = (const int*)d_in[15];
    const int* dst  = (const int*)d_in[16];
    const int* lnid = (const int*)d_in[17];

    float* out = (float*)d_out;

    // ws layout (bytes)
    char* base = (char*)d_ws;
    int*  hist  = (int*) (base + 0);           // 80 KB
    int*  dperm = (int*) (base + 81920);       // -> 1392640
    int*  bc    = (int*) (base + 1392640);     // 16 KB
    int*  bo    = (int*) (base + 1409024);     // 16 KB
    int*  lperm = (int*) (base + 1425408);     // -> 2736128
    int*  lenq  = (int*) (base + 2736128);     // -> 4046848
    uint* wpk   = (uint*)(base + 4046848);     // 40 KB -> 4112384 (padded)
    uint* ewc   = (uint*)(base + 4112384);     // 24.5 KB -> 4145152
    uint* Xpk   = (uint*)(base + 4145152);     // 81.92 MB -> 86065152
    f16*  hb    = (f16*) (base + 86065152);    // 40.96 MB -> 127025152
    f16*  mbuf  = (f16*) (base + 127025152);   // 40.96 MB -> 167985152

    hipMemsetAsync(hist, 0, 81920, stream);

    // length sort (for lstm4 tiles + sorted Xpk)
    count_kernel<<<NBLK, 256, 0, stream>>>(elen, bc);
    offs_kernel<<<1, 256, 0, stream>>>(bc, bo);
    scatter2_kernel<<<NBLK, 256, 0, stream>>>(elen, bo, lperm, lenq);

    // dst sort (for node segment-sum)
    dhist_kernel<<<1250, 256, 0, stream>>>(dst, hist);
    dscan_kernel<<<1, 256, 0, stream>>>(hist);
    dscatter_kernel<<<1250, 256, 0, stream>>>(dst, hist, dperm);

    wprep_kernel<<<40, 256, 0, stream>>>(Whh, Wih, eW, wpk, ewc);
    xprep_kernel<<<10000, 256, 0, stream>>>(ef, st, lperm, Xpk);

    lstm4_kernel<<<2048, 256, 0, stream>>>((const uint4*)wpk, lb, Xpk, lperm, lenq, hb);

    mlp_kernel<<<1024, 256, 0, stream>>>(nf, pw, (const uint4*)ewc, eb, src, hb, mbuf);

    node_kernel<<<512, NB_THREADS, 0, stream>>>(
        nf, sgn, eW, eb, nW, nb, fcW, fcb, lnid, hist, dperm, mbuf, out,
        512 * NB_WAVES);
}